// Round 1
// baseline (124.639 us; speedup 1.0000x reference)
//
#include <hip/hip_runtime.h>

#define NUM_CLASSES 1000
#define ROW_N 512
#define BLOCK 256

__global__ __launch_bounds__(BLOCK) void mode_onehot_kernel(
    const int* __restrict__ in, float* __restrict__ out, int B) {
  __shared__ int cnt[NUM_CLASSES];
  __shared__ int fpos[NUM_CLASSES];
  __shared__ unsigned int red[BLOCK / 64];
  __shared__ int mode_sh;

  const int row = blockIdx.x;
  if (row >= B) return;
  const int tid = threadIdx.x;

  // init histogram
  for (int c = tid; c < NUM_CLASSES; c += BLOCK) {
    cnt[c] = 0;
    fpos[c] = ROW_N;
  }
  __syncthreads();

  // each thread handles 2 consecutive elements (coalesced int2 load)
  const int2* in2 = reinterpret_cast<const int2*>(in + (size_t)row * ROW_N);
  int2 v = in2[tid];
  atomicAdd(&cnt[v.x], 1);
  atomicMin(&fpos[v.x], 2 * tid);
  atomicAdd(&cnt[v.y], 1);
  atomicMin(&fpos[v.y], 2 * tid + 1);
  __syncthreads();

  // argmax over classes; comb = (count*1024 + (512 - first_pos)) << 10 | (1023 - c)
  // key fits: max = (512*1024 + 512) << 10 | 1023 < 2^30
  unsigned int best = 0u;
  for (int c = tid; c < NUM_CLASSES; c += BLOCK) {
    unsigned int key = (unsigned int)cnt[c] * 1024u + (unsigned int)(ROW_N - fpos[c]);
    unsigned int comb = (key << 10) | (unsigned int)(1023 - c);
    best = best > comb ? best : comb;
  }
  // wave (64-lane) butterfly max
  for (int off = 32; off >= 1; off >>= 1) {
    unsigned int o = (unsigned int)__shfl_xor((int)best, off, 64);
    best = best > o ? best : o;
  }
  if ((tid & 63) == 0) red[tid >> 6] = best;
  __syncthreads();
  if (tid == 0) {
    unsigned int b = red[0];
#pragma unroll
    for (int w = 1; w < BLOCK / 64; ++w) b = b > red[w] ? b : red[w];
    mode_sh = 1023 - (int)(b & 1023u);
  }
  __syncthreads();
  const int mode = mode_sh;

  // write one-hot row: 250 float4 stores (row stride 4000 B is 16B-aligned)
  float4* orow = reinterpret_cast<float4*>(out + (size_t)row * NUM_CLASSES);
  const int mj = mode >> 2, mk = mode & 3;
  for (int i = tid; i < NUM_CLASSES / 4; i += BLOCK) {
    float4 z = make_float4(0.f, 0.f, 0.f, 0.f);
    if (i == mj) (&z.x)[mk] = 1.0f;
    orow[i] = z;
  }
}

extern "C" void kernel_launch(void* const* d_in, const int* in_sizes, int n_in,
                              void* d_out, int out_size, void* d_ws, size_t ws_size,
                              hipStream_t stream) {
  const int* in = (const int*)d_in[0];
  float* out = (float*)d_out;
  const int B = in_sizes[0] / ROW_N;  // 65536
  mode_onehot_kernel<<<B, BLOCK, 0, stream>>>(in, out, B);
}

// Round 2
// 104.945 us; speedup vs baseline: 1.1877x; 1.1877x over previous
//
#include <hip/hip_runtime.h>

#define NUM_CLASSES 1000
#define ROW_N 512
#define ROWS_PER_BLOCK 4
#define BLOCK 256

// Kernel 1: per-row mode (one 64-lane wave per row, 4 rows per block).
// Tie-break equivalence proof: reference picks max count, ties to the class
// whose FIRST OCCURRENCE is earliest. Scanning the row left-to-right, the
// first position p whose class has count == M is necessarily the first
// occurrence region of the winning class: any M-count class with an earlier
// first occurrence would occupy an earlier such position. So
// winner = row[min{p : cnt[row[p]] == M}].
__global__ __launch_bounds__(BLOCK) void mode_kernel(
    const int* __restrict__ in, int* __restrict__ modes, int B) {
  __shared__ int cnt[ROWS_PER_BLOCK][NUM_CLASSES];

  const int tid = threadIdx.x;
  const int w = tid >> 6;    // wave id == row slot
  const int lane = tid & 63;
  const int row = blockIdx.x * ROWS_PER_BLOCK + w;

  // Phase 0: zero this wave's histogram (stride-1 -> conflict-free)
  for (int c = lane; c < NUM_CLASSES; c += 64) cnt[w][c] = 0;
  __syncthreads();

  // Phase A: count histogram. Each lane owns 8 consecutive elements,
  // loaded as 2x int4 (32 B/lane in flight -> read-BW saturating).
  const int4* p = reinterpret_cast<const int4*>(in + (size_t)row * ROW_N);
  int4 va = p[2 * lane];
  int4 vb = p[2 * lane + 1];
  atomicAdd(&cnt[w][va.x], 1);
  atomicAdd(&cnt[w][va.y], 1);
  atomicAdd(&cnt[w][va.z], 1);
  atomicAdd(&cnt[w][va.w], 1);
  atomicAdd(&cnt[w][vb.x], 1);
  atomicAdd(&cnt[w][vb.y], 1);
  atomicAdd(&cnt[w][vb.z], 1);
  atomicAdd(&cnt[w][vb.w], 1);
  __syncthreads();

  // Phase B: max count M (wave shuffle reduce)
  int m = 0;
#pragma unroll
  for (int k = 0; k < 16; ++k) {
    int c = lane + 64 * k;
    if (c < NUM_CLASSES) m = max(m, cnt[w][c]);
  }
#pragma unroll
  for (int off = 32; off >= 1; off >>= 1) m = max(m, __shfl_xor(m, off, 64));

  // Phase C: earliest row position whose class has count == M.
  // Elements are already in registers; pack (pos<<10)|class, min-reduce.
  int e[8] = {va.x, va.y, va.z, va.w, vb.x, vb.y, vb.z, vb.w};
  const int base = 8 * lane;
  int best = 0x7FFFFFFF;
#pragma unroll
  for (int j = 0; j < 8; ++j) {
    if (cnt[w][e[j]] == m) best = min(best, ((base + j) << 10) | e[j]);
  }
#pragma unroll
  for (int off = 32; off >= 1; off >>= 1) best = min(best, __shfl_xor(best, off, 64));

  if (lane == 0) modes[row] = best & 1023;
}

// Kernel 2: pure streaming one-hot write (write-BW bound).
__global__ __launch_bounds__(BLOCK) void onehot_kernel(
    const int* __restrict__ modes, float* __restrict__ out, int B) {
  const int tid = threadIdx.x;
  const int row0 = blockIdx.x * ROWS_PER_BLOCK;

  int mode_r[ROWS_PER_BLOCK];
#pragma unroll
  for (int r = 0; r < ROWS_PER_BLOCK; ++r) mode_r[r] = modes[row0 + r];

#pragma unroll
  for (int r = 0; r < ROWS_PER_BLOCK; ++r) {
    const int row = row0 + r;
    float4* orow = reinterpret_cast<float4*>(out + (size_t)row * NUM_CLASSES);
    const int mj = mode_r[r] >> 2, mk = mode_r[r] & 3;
    if (tid < NUM_CLASSES / 4) {
      float4 z = make_float4(0.f, 0.f, 0.f, 0.f);
      if (tid == mj) (&z.x)[mk] = 1.0f;
      orow[tid] = z;
    }
  }
}

extern "C" void kernel_launch(void* const* d_in, const int* in_sizes, int n_in,
                              void* d_out, int out_size, void* d_ws, size_t ws_size,
                              hipStream_t stream) {
  const int* in = (const int*)d_in[0];
  float* out = (float*)d_out;
  int* modes = (int*)d_ws;  // 65536 * 4 B = 256 KB scratch
  const int B = in_sizes[0] / ROW_N;  // 65536

  const int grid = B / ROWS_PER_BLOCK;  // 16384
  mode_kernel<<<grid, BLOCK, 0, stream>>>(in, modes, B);
  onehot_kernel<<<grid, BLOCK, 0, stream>>>(modes, out, B);
}

// Round 3
// 91.996 us; speedup vs baseline: 1.3548x; 1.1408x over previous
//
#include <hip/hip_runtime.h>

#define NUM_CLASSES 1000
#define CPAD 1024          // histogram padded to 1024 for vectorized zero-init
#define ROW_N 512
#define ROWS_PER_BLOCK 4
#define BLOCK 256

// Fused per-row mode + one-hot. One 64-lane wave per row; wave-private
// histogram slice -> NO block-wide barriers at all (same-wave LDS ops are
// in-order; nothing crosses waves).
//
// Tie-break equivalence (matches reference's count + first-occurrence rule):
// winner = row[min{p : cnt[row[p]] == M}] where M = max count. Any position
// p earlier than the winner's first occurrence with cnt==M would itself
// belong to a max-count class with an earlier first occurrence.
//
// M via atomic returns: final count of class c equals the post-increment
// value of the LAST update to c, so M = wave_max over all (old+1).
__global__ __launch_bounds__(BLOCK) void mode_onehot_fused(
    const int* __restrict__ in, float* __restrict__ out) {
  __shared__ int cnt[ROWS_PER_BLOCK][CPAD];

  const int tid = threadIdx.x;
  const int w = tid >> 6;    // wave id == row slot within block
  const int lane = tid & 63;
  const int row = blockIdx.x * ROWS_PER_BLOCK + w;

  // zero wave-private histogram: 4 x ds_write_b128
  int4* cz = reinterpret_cast<int4*>(cnt[w]);
#pragma unroll
  for (int k = 0; k < 4; ++k) cz[lane + 64 * k] = make_int4(0, 0, 0, 0);

  // load row: 2 contiguous int4 instructions (1 KB each)
  const int4* p = reinterpret_cast<const int4*>(in + (size_t)row * ROW_N);
  int4 va = p[lane];
  int4 vb = p[lane + 64];

  // histogram build + running max of post-increment counts
  int m = 0;
  m = max(m, atomicAdd(&cnt[w][va.x], 1) + 1);
  m = max(m, atomicAdd(&cnt[w][va.y], 1) + 1);
  m = max(m, atomicAdd(&cnt[w][va.z], 1) + 1);
  m = max(m, atomicAdd(&cnt[w][va.w], 1) + 1);
  m = max(m, atomicAdd(&cnt[w][vb.x], 1) + 1);
  m = max(m, atomicAdd(&cnt[w][vb.y], 1) + 1);
  m = max(m, atomicAdd(&cnt[w][vb.z], 1) + 1);
  m = max(m, atomicAdd(&cnt[w][vb.w], 1) + 1);
#pragma unroll
  for (int off = 32; off >= 1; off >>= 1) m = max(m, __shfl_xor(m, off, 64));

  // Phase C: earliest position whose class has final count == M.
  // Element positions: va -> 4*lane..4*lane+3, vb -> 256+4*lane..
  int e[8] = {va.x, va.y, va.z, va.w, vb.x, vb.y, vb.z, vb.w};
  int best = 0x7FFFFFFF;
#pragma unroll
  for (int j = 0; j < 8; ++j) {
    const int pos = (j < 4) ? (4 * lane + j) : (256 + 4 * lane + (j - 4));
    if (cnt[w][e[j]] == m) best = min(best, (pos << 10) | e[j]);
  }
#pragma unroll
  for (int off = 32; off >= 1; off >>= 1) best = min(best, __shfl_xor(best, off, 64));

  const int mode = best & 1023;

  // inline one-hot write: 250 float4 stores for this wave's row
  float4* orow = reinterpret_cast<float4*>(out + (size_t)row * NUM_CLASSES);
  const int mj = mode >> 2, mk = mode & 3;
#pragma unroll
  for (int i = lane; i < NUM_CLASSES / 4; i += 64) {
    float4 z = make_float4(0.f, 0.f, 0.f, 0.f);
    if (i == mj) (&z.x)[mk] = 1.0f;
    orow[i] = z;
  }
}

extern "C" void kernel_launch(void* const* d_in, const int* in_sizes, int n_in,
                              void* d_out, int out_size, void* d_ws, size_t ws_size,
                              hipStream_t stream) {
  const int* in = (const int*)d_in[0];
  float* out = (float*)d_out;
  const int B = in_sizes[0] / ROW_N;  // 65536
  mode_onehot_fused<<<B / ROWS_PER_BLOCK, BLOCK, 0, stream>>>(in, out);
}